// Round 1
// baseline (2073.941 us; speedup 1.0000x reference)
//
#include <hip/hip_runtime.h>
#include <math.h>

// Problem constants
#define BB 128
#define SS 64
#define EE 300
#define HH 512
#define LL 5
#define BSH (BB*SS*HH)   // 4,194,304

__device__ __forceinline__ float fast_sigmoid(float x) {
    return 1.0f / (1.0f + __expf(-x));
}
// c can be astronomically large (fc accumulates geometrically); clamp before tanh
// so exp doesn't produce inf/inf. tanh(+-20) == +-1 in fp32.
__device__ __forceinline__ float fast_tanh(float x) {
    x = fminf(fmaxf(x, -20.0f), 20.0f);
    float e = __expf(2.0f * x);
    return (e - 1.0f) / (e + 1.0f);
}

// ---------------------------------------------------------------------------
// XP precompute: XPg[b,s,:] = embed[x[b,s]] @ Wgx.T + bgx + bgh  (biases folded)
// Tiled fp32 GEMM: [8192 x 300] @ [300 x 512], grid.z selects gate.
// ---------------------------------------------------------------------------
__global__ __launch_bounds__(256) void xp_kernel(
    const int* __restrict__ x, const float* __restrict__ embed,
    const float* __restrict__ Wix, const float* __restrict__ Wfx, const float* __restrict__ Wux,
    const float* __restrict__ bix, const float* __restrict__ bih,
    const float* __restrict__ bfx, const float* __restrict__ bfh,
    const float* __restrict__ bux, const float* __restrict__ buh,
    float* __restrict__ XPi, float* __restrict__ XPf, float* __restrict__ XPu)
{
    const int mb = blockIdx.x;   // 128 row tiles (64 rows of B*S)
    const int nb = blockIdx.y;   // 8 col tiles (64 of H)
    const int g  = blockIdx.z;   // gate
    const float* __restrict__ W  = (g == 0) ? Wix : (g == 1) ? Wfx : Wux;
    const float* __restrict__ b1 = (g == 0) ? bix : (g == 1) ? bfx : bux;
    const float* __restrict__ b2 = (g == 0) ? bih : (g == 1) ? bfh : buh;
    float* __restrict__ OUT      = (g == 0) ? XPi : (g == 1) ? XPf : XPu;

    const int row0 = mb * 64, n0 = nb * 64;
    __shared__ float As[64][60];       // A[m][k]
    __shared__ float Bs[60][65];       // B^T with +1 pad (bank-conflict free)
    __shared__ int   toks[64];

    const int tid = threadIdx.x;
    if (tid < 64) toks[tid] = x[row0 + tid];
    __syncthreads();

    const int tx = tid & 15, ty = tid >> 4;   // 16x16 thread grid, 4x4 outs each
    float acc[4][4];
    #pragma unroll
    for (int r = 0; r < 4; ++r)
        #pragma unroll
        for (int c = 0; c < 4; ++c) acc[r][c] = 0.0f;

    for (int kb = 0; kb < 5; ++kb) {          // K = 300 = 5 * 60
        const int k0 = kb * 60;
        for (int i = tid; i < 64 * 60; i += 256) {
            int m = i / 60, k = i - m * 60;
            As[m][k] = embed[(size_t)toks[m] * EE + k0 + k];
        }
        for (int i = tid; i < 60 * 64; i += 256) {
            int n = i / 60, k = i - n * 60;
            Bs[k][n] = W[(size_t)(n0 + n) * EE + k0 + k];
        }
        __syncthreads();
        #pragma unroll 4
        for (int k = 0; k < 60; ++k) {
            float av[4], bv[4];
            #pragma unroll
            for (int r = 0; r < 4; ++r) av[r] = As[ty * 4 + r][k];
            #pragma unroll
            for (int c = 0; c < 4; ++c) bv[c] = Bs[k][tx * 4 + c];
            #pragma unroll
            for (int r = 0; r < 4; ++r)
                #pragma unroll
                for (int c = 0; c < 4; ++c) acc[r][c] += av[r] * bv[c];
        }
        __syncthreads();
    }

    #pragma unroll
    for (int r = 0; r < 4; ++r) {
        int row = row0 + ty * 4 + r;
        #pragma unroll
        for (int c = 0; c < 4; ++c) {
            int n = n0 + tx * 4 + c;
            OUT[(size_t)row * HH + n] = acc[r][c] + b1[n] + b2[n];
        }
    }
}

// ---------------------------------------------------------------------------
// Per-step gates: one block per chain b, thread = one h.
// Gathers cached projections of active (masked & written) children, computes
// gates, writes C[b,cur,:] and hcur[b,:].
// ---------------------------------------------------------------------------
__global__ __launch_bounds__(512) void step_gates(
    const int* __restrict__ bfs, const int* __restrict__ children,
    const float* __restrict__ XPi, const float* __restrict__ XPf, const float* __restrict__ XPu,
    const float* __restrict__ HWih, const float* __restrict__ HWfh, const float* __restrict__ HWuh,
    float* __restrict__ C, float* __restrict__ hcur, int t)
{
    const int b = blockIdx.x;
    const int h = threadIdx.x;
    __shared__ int s_cur, s_cnt;
    __shared__ int s_list[SS];

    if (h == 0) { s_cnt = 0; s_cur = bfs[b * SS + t]; }
    __syncthreads();
    const int cur = s_cur;

    // Build compact active-children list: child mask & already-written.
    // Unwritten nodes have H=0,C=0 -> contribute exactly nothing; skipping is exact.
    if (h < SS) {
        int m = children[(size_t)(b * SS + cur) * SS + h];
        if (m != 0 && t > 0) {
            int w = 0;
            for (int tp = 0; tp < t; ++tp) w |= (bfs[b * SS + tp] == h);
            if (w) { int p = atomicAdd(&s_cnt, 1); s_list[p] = h; }
        }
    }
    __syncthreads();
    const int cnt = s_cnt;

    const size_t xrow = (size_t)(b * SS + cur) * HH + h;
    const float xpi = XPi[xrow];   // xe@Wix.T + bix + bih
    const float xpf = XPf[xrow];   // xe@Wfx.T + bfx + bfh
    const float xpu = XPu[xrow];   // xe@Wux.T + bux + buh

    float aih = 0.0f, afh = 0.0f, auh = 0.0f, fc = 0.0f;
    for (int idx = 0; idx < cnt; ++idx) {
        const int s = s_list[idx];
        const size_t base = (size_t)(b * SS + s) * HH + h;
        float pih = HWih[base];
        float pfh = HWfh[base];
        float puh = HWuh[base];
        float cc  = C[base];
        aih += pih; afh += pfh; auh += puh;
        fc += fast_sigmoid(pfh + xpf) * cc;     // per-child forget * C
    }

    const float ig = fast_sigmoid(xpi + aih);
    const float og = fast_sigmoid(xpf + afh);   // 'o' gate shares fx/fh per source
    const float ug = fast_tanh(xpu + auh);
    const float c  = ig * ug + fc;
    const float hv = og * fast_tanh(c);

    C[(size_t)(b * SS + cur) * HH + h] = c;
    hcur[b * HH + h] = hv;
}

// ---------------------------------------------------------------------------
// Per-step projection GEMM: [128 x 512] @ [512 x 1536] -> scatter to
// HW{ih,fh,uh}[b, cur_b, :]. Weights read once per step device-wide.
// Tile 16x64, 8 M-tiles x 24 N-tiles = 192 blocks.
// ---------------------------------------------------------------------------
__global__ __launch_bounds__(256) void step_proj(
    const float* __restrict__ hcur,
    const float* __restrict__ Wih, const float* __restrict__ Wfh, const float* __restrict__ Wuh,
    const int* __restrict__ bfs,
    float* __restrict__ HWih, float* __restrict__ HWfh, float* __restrict__ HWuh, int t)
{
    const int mb = blockIdx.x;       // 0..7
    const int nb = blockIdx.y;       // 0..23; gate = nb/8
    const int gate = nb >> 3;
    const int n0 = (nb & 7) * 64;
    const float* __restrict__ W = (gate == 0) ? Wih : (gate == 1) ? Wfh : Wuh;
    float* __restrict__ OUT     = (gate == 0) ? HWih : (gate == 1) ? HWfh : HWuh;

    __shared__ float As[16][64];
    __shared__ float Bs[64][65];     // +1 pad

    const int tid  = threadIdx.x;
    const int nloc = tid & 63;       // output column in tile
    const int mgrp = tid >> 6;       // rows mgrp*4 .. mgrp*4+3 (wave-uniform)
    const int b0   = mb * 16;

    float acc0 = 0.f, acc1 = 0.f, acc2 = 0.f, acc3 = 0.f;

    for (int k0 = 0; k0 < HH; k0 += 64) {
        #pragma unroll
        for (int i = 0; i < 4; ++i) {
            int idx = tid + i * 256;
            int m = idx >> 6, k = idx & 63;
            As[m][k] = hcur[(b0 + m) * HH + k0 + k];
        }
        #pragma unroll
        for (int i = 0; i < 16; ++i) {
            int idx = tid + i * 256;
            int n = idx >> 6, k = idx & 63;
            Bs[k][n] = W[(size_t)(n0 + n) * HH + k0 + k];
        }
        __syncthreads();
        #pragma unroll 8
        for (int k = 0; k < 64; ++k) {
            float bv = Bs[k][nloc];
            acc0 += As[mgrp * 4 + 0][k] * bv;   // broadcast reads (wave-uniform)
            acc1 += As[mgrp * 4 + 1][k] * bv;
            acc2 += As[mgrp * 4 + 2][k] * bv;
            acc3 += As[mgrp * 4 + 3][k] * bv;
        }
        __syncthreads();
    }

    float accs[4] = {acc0, acc1, acc2, acc3};
    #pragma unroll
    for (int r = 0; r < 4; ++r) {
        int b = b0 + mgrp * 4 + r;
        int cur = bfs[b * SS + t];
        OUT[(size_t)(b * SS + cur) * HH + n0 + nloc] = accs[r];
    }
}

// ---------------------------------------------------------------------------
// Final projection: out[b,l] = hcur[b,:] . Wout[l,:] + bout[l]
// ---------------------------------------------------------------------------
__global__ __launch_bounds__(64) void out_kernel(
    const float* __restrict__ hcur,
    const float* __restrict__ Wout, const float* __restrict__ bout,
    float* __restrict__ out)
{
    const int b = blockIdx.x;
    const int lane = threadIdx.x;
    float acc[LL];
    #pragma unroll
    for (int l = 0; l < LL; ++l) acc[l] = 0.0f;
    for (int h = lane; h < HH; h += 64) {
        const float hv = hcur[b * HH + h];
        #pragma unroll
        for (int l = 0; l < LL; ++l) acc[l] += hv * Wout[l * HH + h];
    }
    #pragma unroll
    for (int off = 32; off > 0; off >>= 1) {
        #pragma unroll
        for (int l = 0; l < LL; ++l) acc[l] += __shfl_down(acc[l], off);
    }
    if (lane == 0) {
        #pragma unroll
        for (int l = 0; l < LL; ++l) out[b * LL + l] = acc[l] + bout[l];
    }
}

extern "C" void kernel_launch(void* const* d_in, const int* in_sizes, int n_in,
                              void* d_out, int out_size, void* d_ws, size_t ws_size,
                              hipStream_t stream)
{
    (void)in_sizes; (void)n_in; (void)out_size; (void)ws_size;
    const int*   x        = (const int*)d_in[0];
    const int*   bfs      = (const int*)d_in[1];
    const int*   children = (const int*)d_in[2];
    const float* embed    = (const float*)d_in[3];
    const float* Wix = (const float*)d_in[4];
    const float* bix = (const float*)d_in[5];
    const float* Wih = (const float*)d_in[6];
    const float* bih = (const float*)d_in[7];
    const float* Wfx = (const float*)d_in[8];
    const float* bfx = (const float*)d_in[9];
    const float* Wfh = (const float*)d_in[10];
    const float* bfh = (const float*)d_in[11];
    const float* Wux = (const float*)d_in[12];
    const float* bux = (const float*)d_in[13];
    const float* Wuh = (const float*)d_in[14];
    const float* buh = (const float*)d_in[15];
    const float* Wout = (const float*)d_in[16];
    const float* bout = (const float*)d_in[17];
    float* out = (float*)d_out;

    // Workspace layout (floats): 7*BSH + B*H = ~112.3 MiB
    float* ws   = (float*)d_ws;
    float* XPi  = ws;
    float* XPf  = XPi  + BSH;
    float* XPu  = XPf  + BSH;
    float* HWih = XPu  + BSH;
    float* HWfh = HWih + BSH;
    float* HWuh = HWfh + BSH;
    float* Cst  = HWuh + BSH;
    float* hcur = Cst  + BSH;
    // No zero-init needed: gather skips nodes that were never written, and every
    // read slot is written by an earlier kernel in stream order.

    xp_kernel<<<dim3(128, 8, 3), 256, 0, stream>>>(
        x, embed, Wix, Wfx, Wux, bix, bih, bfx, bfh, bux, buh, XPi, XPf, XPu);

    for (int t = 0; t < SS; ++t) {
        step_gates<<<dim3(BB), 512, 0, stream>>>(
            bfs, children, XPi, XPf, XPu, HWih, HWfh, HWuh, Cst, hcur, t);
        step_proj<<<dim3(8, 24), 256, 0, stream>>>(
            hcur, Wih, Wfh, Wuh, bfs, HWih, HWfh, HWuh, t);
    }

    out_kernel<<<dim3(BB), 64, 0, stream>>>(hcur, Wout, bout, out);
}

// Round 3
// 1812.139 us; speedup vs baseline: 1.1445x; 1.1445x over previous
//
#include <hip/hip_runtime.h>
#include <math.h>

// Problem constants
#define BB 128
#define SS 64
#define EE 300
#define HH 512
#define LL 5
#define BSH (BB*SS*HH)   // 4,194,304
#define KP  320          // E padded to multiple of 32 for bf16 MFMA

typedef __attribute__((ext_vector_type(8))) short bf16x8;        // 8 bf16 = 4 VGPRs
typedef __attribute__((ext_vector_type(4))) float f32x4;
typedef __attribute__((ext_vector_type(4))) unsigned int u32x4;  // 16B staging

__device__ __forceinline__ float fast_sigmoid(float x) {
    return 1.0f / (1.0f + __expf(-x));
}
__device__ __forceinline__ float fast_tanh(float x) {
    x = fminf(fmaxf(x, -20.0f), 20.0f);
    float e = __expf(2.0f * x);
    return (e - 1.0f) / (e + 1.0f);
}
// fp32 -> bf16 round-to-nearest-even (bit trick; inputs finite here)
__device__ __forceinline__ unsigned short f2bf(float f) {
    unsigned int u = __float_as_uint(f);
    u += 0x7fffu + ((u >> 16) & 1u);
    return (unsigned short)(u >> 16);
}
__device__ __forceinline__ float bf2f(unsigned short h) {
    return __uint_as_float((unsigned int)h << 16);
}
// Split fp32 into hi/lo bf16 pair: v ~= hi + lo, residual ~2^-18 * |v|
__device__ __forceinline__ void split2(float v, unsigned short& hi, unsigned short& lo) {
    hi = f2bf(v);
    lo = f2bf(v - bf2f(hi));
}

// ---------------------------------------------------------------------------
// Prep: (a) split 6 weight matrices into bf16 hi/lo planes (Wx padded K->320),
// (b) per-(b,t) compact active-children lists (child mask AND written-before-t).
// ---------------------------------------------------------------------------
__global__ __launch_bounds__(256) void prep_kernel(
    const int* __restrict__ bfs, const int* __restrict__ children,
    const float* __restrict__ Wix, const float* __restrict__ Wfx, const float* __restrict__ Wux,
    const float* __restrict__ Wih, const float* __restrict__ Wfh, const float* __restrict__ Wuh,
    unsigned short* __restrict__ Wixh, unsigned short* __restrict__ Wixl,
    unsigned short* __restrict__ Wfxh, unsigned short* __restrict__ Wfxl,
    unsigned short* __restrict__ Wuxh, unsigned short* __restrict__ Wuxl,
    unsigned short* __restrict__ Wihh, unsigned short* __restrict__ Wihl,
    unsigned short* __restrict__ Wfhh, unsigned short* __restrict__ Wfhl,
    unsigned short* __restrict__ Wuhh, unsigned short* __restrict__ Wuhl,
    unsigned char* __restrict__ clist, int* __restrict__ ccnt)
{
    const int gid = blockIdx.x * 256 + threadIdx.x;
    const int G = gridDim.x * 256;
    for (int i = gid; i < 3 * HH * KP; i += G) {
        int g = i / (HH * KP), rem = i % (HH * KP), r = rem / KP, k = rem % KP;
        const float* src = (g == 0) ? Wix : (g == 1) ? Wfx : Wux;
        unsigned short* dh = (g == 0) ? Wixh : (g == 1) ? Wfxh : Wuxh;
        unsigned short* dl = (g == 0) ? Wixl : (g == 1) ? Wfxl : Wuxl;
        float v = (k < EE) ? src[(size_t)r * EE + k] : 0.0f;
        unsigned short hi, lo; split2(v, hi, lo);
        dh[r * KP + k] = hi; dl[r * KP + k] = lo;
    }
    for (int i = gid; i < 3 * HH * HH; i += G) {
        int g = i / (HH * HH), idx = i % (HH * HH);
        const float* src = (g == 0) ? Wih : (g == 1) ? Wfh : Wuh;
        unsigned short* dh = (g == 0) ? Wihh : (g == 1) ? Wfhh : Wuhh;
        unsigned short* dl = (g == 0) ? Wihl : (g == 1) ? Wfhl : Wuhl;
        unsigned short hi, lo; split2(src[idx], hi, lo);
        dh[idx] = hi; dl[idx] = lo;
    }
    if (gid < BB * SS) {
        const int b = gid >> 6, t = gid & 63;
        unsigned long long w = 0;
        for (int tp = 0; tp < t; ++tp) w |= 1ull << (bfs[b * SS + tp] & 63);
        const int cur = bfs[b * SS + t];
        const int* crow = children + (size_t)(b * SS + cur) * SS;
        unsigned char* lst = clist + (size_t)gid * SS;
        int cnt = 0;
        for (int s = 0; s < SS; ++s)
            if (crow[s] != 0 && ((w >> s) & 1ull)) lst[cnt++] = (unsigned char)s;
        ccnt[gid] = cnt;
    }
}

// ---------------------------------------------------------------------------
// XP precompute, split-bf16 MFMA (fp32-equivalent):
//   XPg[b,s,:] = embed[x[b,s]] @ Wgx.T + bgx + bgh
// [8192 x 320pad] @ [320 x 512] per gate. Tile 32M x 64N, grid (256, 3).
// A staged full-K as hi/lo planes; B staged per (nt,kc) 64x64 chunk hi/lo.
// D = Ah*Bh + Ah*Bl + Al*Bh  (lo*lo dropped, rel ~2^-18).
// ---------------------------------------------------------------------------
__global__ __launch_bounds__(256) void xp_mfma(
    const int* __restrict__ x, const float* __restrict__ embed,
    const unsigned short* __restrict__ Wixh, const unsigned short* __restrict__ Wixl,
    const unsigned short* __restrict__ Wfxh, const unsigned short* __restrict__ Wfxl,
    const unsigned short* __restrict__ Wuxh, const unsigned short* __restrict__ Wuxl,
    const float* __restrict__ bix, const float* __restrict__ bih,
    const float* __restrict__ bfx, const float* __restrict__ bfh,
    const float* __restrict__ bux, const float* __restrict__ buh,
    float* __restrict__ XPi, float* __restrict__ XPf, float* __restrict__ XPu)
{
    const int mb = blockIdx.x;            // 256 tiles of 32 rows of B*S
    const int g  = blockIdx.y;            // gate
    const unsigned short* __restrict__ Wbh = (g == 0) ? Wixh : (g == 1) ? Wfxh : Wuxh;
    const unsigned short* __restrict__ Wbl = (g == 0) ? Wixl : (g == 1) ? Wfxl : Wuxl;
    const float* __restrict__ b1 = (g == 0) ? bix : (g == 1) ? bfx : bux;
    const float* __restrict__ b2 = (g == 0) ? bih : (g == 1) ? bfh : buh;
    float* __restrict__ OUT = (g == 0) ? XPi : (g == 1) ? XPf : XPu;

    const int row0 = mb * 32;
    __shared__ unsigned short As[2][32 * 328];   // hi/lo planes, full K, pad 328
    __shared__ unsigned short Bs[2][64 * 72];    // hi/lo planes, 64-K chunk, pad 72
    __shared__ int toks[32];

    const int tid = threadIdx.x;
    if (tid < 32) toks[tid] = x[row0 + tid];
    __syncthreads();

    // Stage A full K: 32 rows x 300 fp32 (75 float4 each) -> split into planes
    for (int i = tid; i < 32 * 75; i += 256) {
        int r = i / 75, c = i - r * 75;
        const float4 v = *(const float4*)(embed + (size_t)toks[r] * EE + c * 4);
        ushort4 hv, lv;
        split2(v.x, hv.x, lv.x); split2(v.y, hv.y, lv.y);
        split2(v.z, hv.z, lv.z); split2(v.w, hv.w, lv.w);
        *(ushort4*)&As[0][r * 328 + c * 4] = hv;
        *(ushort4*)&As[1][r * 328 + c * 4] = lv;
    }
    for (int i = tid; i < 32 * 20; i += 256) {
        int r = i / 20, k = EE + (i - r * 20);
        As[0][r * 328 + k] = 0; As[1][r * 328 + k] = 0;
    }

    const int lane = tid & 63, wave = tid >> 6;
    const int quad = lane >> 4, col = lane & 15;
    const int wn = wave * 16;             // each wave: 16-wide N-slice, full 32 M

    for (int nt = 0; nt < 8; ++nt) {
        const int n0g = nt * 64;
        f32x4 acc0 = {0.f, 0.f, 0.f, 0.f}, acc1 = {0.f, 0.f, 0.f, 0.f};
        for (int kc = 0; kc < 5; ++kc) {            // K = 320 = 5 * 64
            const int k0 = kc * 64;
            __syncthreads();   // guard Bs overwrite (covers As/toks on first iter)
            for (int i = tid; i < 1024; i += 256) {
                int plane = i >> 9, j = i & 511, r = j >> 3, c = j & 7;
                const unsigned short* W = plane ? Wbl : Wbh;
                *(u32x4*)&Bs[plane][r * 72 + c * 8] =
                    *(const u32x4*)(W + (size_t)(n0g + r) * KP + k0 + c * 8);
            }
            __syncthreads();
            #pragma unroll
            for (int kq = 0; kq < 2; ++kq) {
                const int kaA = k0 + kq * 32 + quad * 8;
                const int kaB = kq * 32 + quad * 8;
                bf16x8 a0h = *(const bf16x8*)&As[0][col * 328 + kaA];
                bf16x8 a0l = *(const bf16x8*)&As[1][col * 328 + kaA];
                bf16x8 a1h = *(const bf16x8*)&As[0][(16 + col) * 328 + kaA];
                bf16x8 a1l = *(const bf16x8*)&As[1][(16 + col) * 328 + kaA];
                bf16x8 bh  = *(const bf16x8*)&Bs[0][(wn + col) * 72 + kaB];
                bf16x8 bl  = *(const bf16x8*)&Bs[1][(wn + col) * 72 + kaB];
                acc0 = __builtin_amdgcn_mfma_f32_16x16x32_bf16(a0h, bh, acc0, 0, 0, 0);
                acc0 = __builtin_amdgcn_mfma_f32_16x16x32_bf16(a0h, bl, acc0, 0, 0, 0);
                acc0 = __builtin_amdgcn_mfma_f32_16x16x32_bf16(a0l, bh, acc0, 0, 0, 0);
                acc1 = __builtin_amdgcn_mfma_f32_16x16x32_bf16(a1h, bh, acc1, 0, 0, 0);
                acc1 = __builtin_amdgcn_mfma_f32_16x16x32_bf16(a1h, bl, acc1, 0, 0, 0);
                acc1 = __builtin_amdgcn_mfma_f32_16x16x32_bf16(a1l, bh, acc1, 0, 0, 0);
            }
        }
        // C/D layout: col = lane&15 (N), row = quad*4 + reg (M)
        const int gn = n0g + wn + col;
        const float bb = b1[gn] + b2[gn];
        #pragma unroll
        for (int reg = 0; reg < 4; ++reg) {
            const int ml = quad * 4 + reg;
            OUT[(size_t)(row0 + ml) * HH + gn]      = acc0[reg] + bb;
            OUT[(size_t)(row0 + 16 + ml) * HH + gn] = acc1[reg] + bb;
        }
    }
}

// ---------------------------------------------------------------------------
// Per-step gates: one block per chain b, 256 threads x 2 h-elems.
// Gathers fp32 cached projections + C over precomputed child lists; writes
// C fp32, h fp32 (for out_kernel) and h hi/lo bf16 planes (for proj MFMA).
// ---------------------------------------------------------------------------
__global__ __launch_bounds__(256) void gates_kernel(
    const int* __restrict__ bfs, const unsigned char* __restrict__ clist,
    const int* __restrict__ ccnt,
    const float* __restrict__ XPi, const float* __restrict__ XPf, const float* __restrict__ XPu,
    const float* __restrict__ HWi, const float* __restrict__ HWf, const float* __restrict__ HWu,
    float* __restrict__ C, float* __restrict__ hf32,
    unsigned short* __restrict__ h_hi, unsigned short* __restrict__ h_lo, int t)
{
    const int b = blockIdx.x, tid = threadIdx.x;
    __shared__ int s_list[SS];
    __shared__ int s_cur, s_cnt;
    const int bt = b * SS + t;
    if (tid == 0) { s_cur = bfs[bt]; s_cnt = ccnt[bt]; }
    if (tid < SS) s_list[tid] = clist[(size_t)bt * SS + tid];
    __syncthreads();
    const int cur = s_cur, cnt = s_cnt;

    const int h2 = tid * 2;
    const size_t xb = (size_t)(b * SS + cur) * HH + h2;
    const float2 xpi = *(const float2*)(XPi + xb);   // xe@Wix.T + bix + bih
    const float2 xpf = *(const float2*)(XPf + xb);   // xe@Wfx.T + bfx + bfh
    const float2 xpu = *(const float2*)(XPu + xb);   // xe@Wux.T + bux + buh

    float ai0 = 0.f, ai1 = 0.f, af0 = 0.f, af1 = 0.f;
    float au0 = 0.f, au1 = 0.f, fc0 = 0.f, fc1 = 0.f;
    for (int idx = 0; idx < cnt; ++idx) {
        const size_t cb = (size_t)(b * SS + s_list[idx]) * HH + h2;
        const float2 pi = *(const float2*)(HWi + cb);
        const float2 pf = *(const float2*)(HWf + cb);
        const float2 pu = *(const float2*)(HWu + cb);
        const float2 cc = *(const float2*)(C + cb);
        ai0 += pi.x; ai1 += pi.y;
        au0 += pu.x; au1 += pu.y;
        af0 += pf.x; af1 += pf.y;
        fc0 += fast_sigmoid(pf.x + xpf.x) * cc.x;     // per-child forget * C
        fc1 += fast_sigmoid(pf.y + xpf.y) * cc.y;
    }

    const float i0 = fast_sigmoid(xpi.x + ai0), i1 = fast_sigmoid(xpi.y + ai1);
    const float o0 = fast_sigmoid(xpf.x + af0), o1 = fast_sigmoid(xpf.y + af1);
    const float u0 = fast_tanh(xpu.x + au0),    u1 = fast_tanh(xpu.y + au1);
    const float c0 = i0 * u0 + fc0, c1 = i1 * u1 + fc1;
    const float h0 = o0 * fast_tanh(c0), h1 = o1 * fast_tanh(c1);

    *(float2*)(C + xb) = make_float2(c0, c1);
    *(float2*)(hf32 + (size_t)b * HH + h2) = make_float2(h0, h1);
    unsigned short h0h, h0l, h1h, h1l;
    split2(h0, h0h, h0l); split2(h1, h1h, h1l);
    *(unsigned int*)(h_hi + (size_t)b * HH + h2) = ((unsigned int)h1h << 16) | h0h;
    *(unsigned int*)(h_lo + (size_t)b * HH + h2) = ((unsigned int)h1l << 16) | h0l;
}

// ---------------------------------------------------------------------------
// Per-step projection, split-bf16 MFMA: [128 x 512] @ [512 x 1536] -> scatter
// fp32 rows HW{ih,fh,uh}[b, cur_b, :]. 192 blocks: 8 M-tiles(16) x 24 N-tiles(64).
// ---------------------------------------------------------------------------
__global__ __launch_bounds__(256) void proj_mfma(
    const unsigned short* __restrict__ h_hi, const unsigned short* __restrict__ h_lo,
    const int* __restrict__ bfs,
    const unsigned short* __restrict__ Wihh, const unsigned short* __restrict__ Wihl,
    const unsigned short* __restrict__ Wfhh, const unsigned short* __restrict__ Wfhl,
    const unsigned short* __restrict__ Wuhh, const unsigned short* __restrict__ Wuhl,
    float* __restrict__ HWi, float* __restrict__ HWf, float* __restrict__ HWu, int t)
{
    const int mt = blockIdx.x & 7;         // 8 M-tiles of 16
    const int nt = blockIdx.x >> 3;        // 24 N-tiles of 64; gate = nt>>3
    const int gate = nt >> 3;
    const int n0 = (nt & 7) * 64;
    const unsigned short* __restrict__ Wbh = (gate == 0) ? Wihh : (gate == 1) ? Wfhh : Wuhh;
    const unsigned short* __restrict__ Wbl = (gate == 0) ? Wihl : (gate == 1) ? Wfhl : Wuhl;
    float* __restrict__ OUT = (gate == 0) ? HWi : (gate == 1) ? HWf : HWu;
    const int m0 = mt * 16;

    __shared__ unsigned short As[2][16 * 72];   // hi/lo, 64-K chunk, pad 72
    __shared__ unsigned short Bs[2][64 * 72];
    __shared__ int s_cur[16];

    const int tid = threadIdx.x;
    if (tid < 16) s_cur[tid] = bfs[(m0 + tid) * SS + t];

    const int lane = tid & 63, wave = tid >> 6;
    const int quad = lane >> 4, col = lane & 15;
    const int wn = wave * 16;              // each wave: 16-wide N-slice, 16 M

    f32x4 acc = {0.f, 0.f, 0.f, 0.f};

    for (int kc = 0; kc < 8; ++kc) {       // K = 512 = 8 * 64
        const int k0 = kc * 64;
        __syncthreads();                    // guard As/Bs overwrite (covers s_cur on iter 0)
        {   // stage A chunk: 2 planes x 16 rows x 8 vec8 = 256 loads, 1/thread
            const int plane = tid >> 7, j = tid & 127, r = j >> 3, c = j & 7;
            const unsigned short* src = plane ? h_lo : h_hi;
            *(u32x4*)&As[plane][r * 72 + c * 8] =
                *(const u32x4*)(src + (size_t)(m0 + r) * HH + k0 + c * 8);
        }
        for (int i = tid; i < 1024; i += 256) {   // B chunk: 2 x 64 x 8 vec8
            const int plane = i >> 9, j = i & 511, r = j >> 3, c = j & 7;
            const unsigned short* src = plane ? Wbl : Wbh;
            *(u32x4*)&Bs[plane][r * 72 + c * 8] =
                *(const u32x4*)(src + (size_t)(n0 + r) * HH + k0 + c * 8);
        }
        __syncthreads();
        #pragma unroll
        for (int kq = 0; kq < 2; ++kq) {
            const int ka = kq * 32 + quad * 8;
            bf16x8 ah = *(const bf16x8*)&As[0][col * 72 + ka];
            bf16x8 al = *(const bf16x8*)&As[1][col * 72 + ka];
            bf16x8 bh = *(const bf16x8*)&Bs[0][(wn + col) * 72 + ka];
            bf16x8 bl = *(const bf16x8*)&Bs[1][(wn + col) * 72 + ka];
            acc = __builtin_amdgcn_mfma_f32_16x16x32_bf16(ah, bh, acc, 0, 0, 0);
            acc = __builtin_amdgcn_mfma_f32_16x16x32_bf16(ah, bl, acc, 0, 0, 0);
            acc = __builtin_amdgcn_mfma_f32_16x16x32_bf16(al, bh, acc, 0, 0, 0);
        }
    }

    #pragma unroll
    for (int reg = 0; reg < 4; ++reg) {
        const int m = quad * 4 + reg;
        const int b = m0 + m;
        const int n = n0 + wn + col;
        OUT[(size_t)(b * SS + s_cur[m]) * HH + n] = acc[reg];
    }
}

// ---------------------------------------------------------------------------
// Final projection: out[b,l] = hcur[b,:] . Wout[l,:] + bout[l]  (fp32)
// ---------------------------------------------------------------------------
__global__ __launch_bounds__(64) void out_kernel(
    const float* __restrict__ hcur,
    const float* __restrict__ Wout, const float* __restrict__ bout,
    float* __restrict__ out)
{
    const int b = blockIdx.x;
    const int lane = threadIdx.x;
    float acc[LL];
    #pragma unroll
    for (int l = 0; l < LL; ++l) acc[l] = 0.0f;
    for (int h = lane; h < HH; h += 64) {
        const float hv = hcur[(size_t)b * HH + h];
        #pragma unroll
        for (int l = 0; l < LL; ++l) acc[l] += hv * Wout[l * HH + h];
    }
    #pragma unroll
    for (int off = 32; off > 0; off >>= 1) {
        #pragma unroll
        for (int l = 0; l < LL; ++l) acc[l] += __shfl_down(acc[l], off);
    }
    if (lane == 0) {
        #pragma unroll
        for (int l = 0; l < LL; ++l) out[b * LL + l] = acc[l] + bout[l];
    }
}

extern "C" void kernel_launch(void* const* d_in, const int* in_sizes, int n_in,
                              void* d_out, int out_size, void* d_ws, size_t ws_size,
                              hipStream_t stream)
{
    (void)in_sizes; (void)n_in; (void)out_size; (void)ws_size;
    const int*   x        = (const int*)d_in[0];
    const int*   bfs      = (const int*)d_in[1];
    const int*   children = (const int*)d_in[2];
    const float* embed    = (const float*)d_in[3];
    const float* Wix = (const float*)d_in[4];
    const float* bix = (const float*)d_in[5];
    const float* Wih = (const float*)d_in[6];
    const float* bih = (const float*)d_in[7];
    const float* Wfx = (const float*)d_in[8];
    const float* bfx = (const float*)d_in[9];
    const float* Wfh = (const float*)d_in[10];
    const float* bfh = (const float*)d_in[11];
    const float* Wux = (const float*)d_in[12];
    const float* bux = (const float*)d_in[13];
    const float* Wuh = (const float*)d_in[14];
    const float* buh = (const float*)d_in[15];
    const float* Wout = (const float*)d_in[16];
    const float* bout = (const float*)d_in[17];
    float* out = (float*)d_out;

    // Workspace layout (~124 MB; every chunk size is a multiple of 256 B)
    char* p = (char*)d_ws;
    float* XPi = (float*)p;            p += (size_t)BSH * 4;
    float* XPf = (float*)p;            p += (size_t)BSH * 4;
    float* XPu = (float*)p;            p += (size_t)BSH * 4;
    float* Cst = (float*)p;            p += (size_t)BSH * 4;
    float* HWi = (float*)p;            p += (size_t)BSH * 4;
    float* HWf = (float*)p;            p += (size_t)BSH * 4;
    float* HWu = (float*)p;            p += (size_t)BSH * 4;
    float* hf32 = (float*)p;           p += (size_t)BB * HH * 4;
    unsigned short* h_hi = (unsigned short*)p; p += (size_t)BB * HH * 2;
    unsigned short* h_lo = (unsigned short*)p; p += (size_t)BB * HH * 2;
    unsigned short* Wixh = (unsigned short*)p; p += (size_t)HH * KP * 2;
    unsigned short* Wixl = (unsigned short*)p; p += (size_t)HH * KP * 2;
    unsigned short* Wfxh = (unsigned short*)p; p += (size_t)HH * KP * 2;
    unsigned short* Wfxl = (unsigned short*)p; p += (size_t)HH * KP * 2;
    unsigned short* Wuxh = (unsigned short*)p; p += (size_t)HH * KP * 2;
    unsigned short* Wuxl = (unsigned short*)p; p += (size_t)HH * KP * 2;
    unsigned short* Wihh = (unsigned short*)p; p += (size_t)HH * HH * 2;
    unsigned short* Wihl = (unsigned short*)p; p += (size_t)HH * HH * 2;
    unsigned short* Wfhh = (unsigned short*)p; p += (size_t)HH * HH * 2;
    unsigned short* Wfhl = (unsigned short*)p; p += (size_t)HH * HH * 2;
    unsigned short* Wuhh = (unsigned short*)p; p += (size_t)HH * HH * 2;
    unsigned short* Wuhl = (unsigned short*)p; p += (size_t)HH * HH * 2;
    unsigned char* clist = (unsigned char*)p;  p += (size_t)BB * SS * SS;
    int* ccnt = (int*)p;               p += (size_t)BB * SS * 4;
    // No zero-init needed: gather only touches slots written earlier this call.

    prep_kernel<<<dim3(256), 256, 0, stream>>>(
        bfs, children, Wix, Wfx, Wux, Wih, Wfh, Wuh,
        Wixh, Wixl, Wfxh, Wfxl, Wuxh, Wuxl,
        Wihh, Wihl, Wfhh, Wfhl, Wuhh, Wuhl, clist, ccnt);

    xp_mfma<<<dim3(256, 3), 256, 0, stream>>>(
        x, embed, Wixh, Wixl, Wfxh, Wfxl, Wuxh, Wuxl,
        bix, bih, bfx, bfh, bux, buh, XPi, XPf, XPu);

    for (int t = 0; t < SS; ++t) {
        gates_kernel<<<dim3(BB), 256, 0, stream>>>(
            bfs, clist, ccnt, XPi, XPf, XPu, HWi, HWf, HWu,
            Cst, hf32, h_hi, h_lo, t);
        if (t < SS - 1) {
            proj_mfma<<<dim3(192), 256, 0, stream>>>(
                h_hi, h_lo, bfs, Wihh, Wihl, Wfhh, Wfhl, Wuhh, Wuhl,
                HWi, HWf, HWu, t);
        }
    }

    out_kernel<<<dim3(BB), 64, 0, stream>>>(hf32, Wout, bout, out);
}